// Round 2
// baseline (7191.460 us; speedup 1.0000x reference)
//
#include <hip/hip_runtime.h>
#include <hip/hip_bf16.h>

#define Bb   2
#define Ss   2048
#define Dd   2048
#define Hh   16
#define KVHh 4
#define HDd  128

#define BM 64
#define BN 64
#define BK 16

// C[M,N] fp32 = A[M,K] fp32 @ B[K,N] fp32, row-major
__global__ __launch_bounds__(256)
void gemm_f32(const float* __restrict__ A, const float* __restrict__ Bm,
              float* __restrict__ C, int M, int N, int K)
{
    __shared__ float sA[BK][BM + 1];
    __shared__ float sB[BK][BN + 1];
    int t  = threadIdx.x;
    int tx = t & 15, ty = t >> 4;
    int m0 = blockIdx.y * BM, n0 = blockIdx.x * BN;

    int ar = t >> 2;            // 0..63
    int ac = (t & 3) * 4;       // 0,4,8,12
    int br = t >> 4;            // 0..15
    int bc = (t & 15) * 4;      // 0..60

    float acc[4][4] = {};

    for (int k0 = 0; k0 < K; k0 += BK) {
        float4 av = *reinterpret_cast<const float4*>(A + (size_t)(m0 + ar) * K + k0 + ac);
        sA[ac + 0][ar] = av.x;
        sA[ac + 1][ar] = av.y;
        sA[ac + 2][ar] = av.z;
        sA[ac + 3][ar] = av.w;
        float4 bv = *reinterpret_cast<const float4*>(Bm + (size_t)(k0 + br) * N + n0 + bc);
        sB[br][bc + 0] = bv.x;
        sB[br][bc + 1] = bv.y;
        sB[br][bc + 2] = bv.z;
        sB[br][bc + 3] = bv.w;
        __syncthreads();
        #pragma unroll
        for (int kk = 0; kk < BK; ++kk) {
            float a[4], b[4];
            #pragma unroll
            for (int r = 0; r < 4; ++r) a[r] = sA[kk][ty * 4 + r];
            #pragma unroll
            for (int c = 0; c < 4; ++c) b[c] = sB[kk][tx * 4 + c];
            #pragma unroll
            for (int r = 0; r < 4; ++r)
                #pragma unroll
                for (int c = 0; c < 4; ++c)
                    acc[r][c] += a[r] * b[c];
        }
        __syncthreads();
    }
    #pragma unroll
    for (int r = 0; r < 4; ++r)
        #pragma unroll
        for (int c = 0; c < 4; ++c)
            C[(size_t)(m0 + ty * 4 + r) * N + n0 + tx * 4 + c] = acc[r][c];
}

// In-place RoPE on X laid out [B*S, nh, 128]; each thread handles pair (i, i+64)
__global__ __launch_bounds__(256)
void rope_kernel(float* __restrict__ X, const float* __restrict__ cosT,
                 const float* __restrict__ sinT, int nh, int total)
{
    int idx = blockIdx.x * blockDim.x + threadIdx.x;
    if (idx >= total) return;
    int i   = idx & 63;
    int rh  = idx >> 6;          // (b*S+s)*nh + h
    int row = rh / nh;           // b*S + s
    int s   = row & (Ss - 1);
    float* xp = X + (size_t)rh * HDd;
    float x1 = xp[i];
    float x2 = xp[i + 64];
    float c1 = cosT[s * HDd + i];
    float c2 = cosT[s * HDd + i + 64];
    float s1 = sinT[s * HDd + i];
    float s2 = sinT[s * HDd + i + 64];
    xp[i]      = x1 * c1 - x2 * s1;
    xp[i + 64] = x2 * c2 + x1 * s2;
}

// One block per (q, h, b): causal softmax(QK^T*scale + alibi + mask) @ V
__global__ __launch_bounds__(256)
void attn_kernel(const float* __restrict__ Q, const float* __restrict__ K,
                 const float* __restrict__ V, const float* __restrict__ alibi,
                 const float* __restrict__ amask, float* __restrict__ ctx)
{
    int q = blockIdx.x, h = blockIdx.y, b = blockIdx.z;
    int kvh = h >> 2;            // h / (H/KVH)
    int t = threadIdx.x;
    __shared__ float ql[HDd];
    __shared__ float p[Ss];
    __shared__ float red[256];
    const float scale = 0.08838834764831845f;   // 1/sqrt(128)

    if (t < HDd)
        ql[t] = Q[(((size_t)b * Ss + q) * Hh + h) * HDd + t] * scale;
    __syncthreads();

    int nk = q + 1;              // causal: keys 0..q (exp(-1e9-m)==0 exactly in fp32)
    float lmax = -3.0e38f;
    for (int k = t; k < nk; k += 256) {
        const float4* kr = reinterpret_cast<const float4*>(
            K + (((size_t)b * Ss + k) * KVHh + kvh) * HDd);
        float dot = 0.f;
        #pragma unroll 8
        for (int d4 = 0; d4 < 32; ++d4) {
            float4 kv = kr[d4];
            dot += ql[d4 * 4 + 0] * kv.x + ql[d4 * 4 + 1] * kv.y +
                   ql[d4 * 4 + 2] * kv.z + ql[d4 * 4 + 3] * kv.w;
        }
        float sc = dot + alibi[((size_t)b * Ss + q) * Ss + k] + amask[b * Ss + k];
        p[k] = sc;
        lmax = fmaxf(lmax, sc);
    }
    red[t] = lmax; __syncthreads();
    for (int off = 128; off > 0; off >>= 1) {
        if (t < off) red[t] = fmaxf(red[t], red[t + off]);
        __syncthreads();
    }
    float m = red[0];
    __syncthreads();

    float lsum = 0.f;
    for (int k = t; k < nk; k += 256) {
        float e = expf(p[k] - m);
        p[k] = e;
        lsum += e;
    }
    red[t] = lsum; __syncthreads();
    for (int off = 128; off > 0; off >>= 1) {
        if (t < off) red[t] += red[t + off];
        __syncthreads();
    }
    float inv = 1.f / red[0];
    __syncthreads();

    // PV: thread (d, half) sums keys with k%2==half; coalesced V reads across d
    int d = t & 127, half = t >> 7;
    float acc = 0.f;
    for (int k = half; k < nk; k += 2)
        acc += p[k] * V[(((size_t)b * Ss + k) * KVHh + kvh) * HDd + d];
    red[t] = acc; __syncthreads();
    if (t < 128)
        ctx[(((size_t)b * Ss + q) * Hh + h) * HDd + t] = (red[t] + red[t + 128]) * inv;
}

extern "C" void kernel_launch(void* const* d_in, const int* in_sizes, int n_in,
                              void* d_out, int out_size, void* d_ws, size_t ws_size,
                              hipStream_t stream) {
    const float* hidden = (const float*)d_in[0];
    const float* cosT   = (const float*)d_in[1];
    const float* sinT   = (const float*)d_in[2];
    const float* alibi  = (const float*)d_in[3];
    const float* amask  = (const float*)d_in[4];
    const float* wq     = (const float*)d_in[5];
    const float* wk     = (const float*)d_in[6];
    const float* wv     = (const float*)d_in[7];
    const float* wo     = (const float*)d_in[8];
    float* out = (float*)d_out;

    float* Qf  = (float*)d_ws;                         // [B,S,H,HD]   8.39M f32
    float* Kf  = Qf + (size_t)Bb * Ss * Hh * HDd;      // [B,S,KVH,HD] 2.10M f32
    float* Vf  = Kf + (size_t)Bb * Ss * KVHh * HDd;    // [B,S,KVH,HD] 2.10M f32
    float* Cf  = Vf + (size_t)Bb * Ss * KVHh * HDd;    // [B,S,H,HD]   8.39M f32
    // total ws use: 83.9 MB

    int M = Bb * Ss;  // 4096

    gemm_f32<<<dim3(Dd / BN, M / BM), 256, 0, stream>>>(hidden, wq, Qf, M, Dd, Dd);
    gemm_f32<<<dim3((KVHh * HDd) / BN, M / BM), 256, 0, stream>>>(hidden, wk, Kf, M, KVHh * HDd, Dd);
    gemm_f32<<<dim3((KVHh * HDd) / BN, M / BM), 256, 0, stream>>>(hidden, wv, Vf, M, KVHh * HDd, Dd);

    int totQ = Bb * Ss * Hh * 64;
    rope_kernel<<<totQ / 256, 256, 0, stream>>>(Qf, cosT, sinT, Hh, totQ);
    int totK = Bb * Ss * KVHh * 64;
    rope_kernel<<<totK / 256, 256, 0, stream>>>(Kf, cosT, sinT, KVHh, totK);

    attn_kernel<<<dim3(Ss, Hh, Bb), 256, 0, stream>>>(Qf, Kf, Vf, alibi, amask, Cf);

    gemm_f32<<<dim3(Dd / BN, M / BM), 256, 0, stream>>>(Cf, wo, out, M, Dd, Dd);
}

// Round 3
// 2288.462 us; speedup vs baseline: 3.1425x; 3.1425x over previous
//
#include <hip/hip_runtime.h>
#include <hip/hip_bf16.h>

#define Bb   2
#define Ss   2048
#define Dd   2048
#define Hh   16
#define KVHh 4
#define HDd  128

#define BM 64
#define BN 64
#define BK 16

typedef __bf16 bf16x8 __attribute__((ext_vector_type(8)));
typedef float f32x4 __attribute__((ext_vector_type(4)));

__device__ __forceinline__ unsigned short f2bf(float f) {
    unsigned u = __float_as_uint(f);
    unsigned r = (u + 0x7FFFu + ((u >> 16) & 1u)) >> 16;   // RNE
    return (unsigned short)r;
}

// C[M,N] fp32 = A[M,K] fp32 @ B[K,N] fp32, row-major
__global__ __launch_bounds__(256)
void gemm_f32(const float* __restrict__ A, const float* __restrict__ Bm,
              float* __restrict__ C, int M, int N, int K)
{
    __shared__ float sA[BK][BM + 1];
    __shared__ float sB[BK][BN + 1];
    int t  = threadIdx.x;
    int tx = t & 15, ty = t >> 4;
    int m0 = blockIdx.y * BM, n0 = blockIdx.x * BN;

    int ar = t >> 2;            // 0..63
    int ac = (t & 3) * 4;       // 0,4,8,12
    int br = t >> 4;            // 0..15
    int bc = (t & 15) * 4;      // 0..60

    float acc[4][4] = {};

    for (int k0 = 0; k0 < K; k0 += BK) {
        float4 av = *reinterpret_cast<const float4*>(A + (size_t)(m0 + ar) * K + k0 + ac);
        sA[ac + 0][ar] = av.x;
        sA[ac + 1][ar] = av.y;
        sA[ac + 2][ar] = av.z;
        sA[ac + 3][ar] = av.w;
        float4 bv = *reinterpret_cast<const float4*>(Bm + (size_t)(k0 + br) * N + n0 + bc);
        sB[br][bc + 0] = bv.x;
        sB[br][bc + 1] = bv.y;
        sB[br][bc + 2] = bv.z;
        sB[br][bc + 3] = bv.w;
        __syncthreads();
        #pragma unroll
        for (int kk = 0; kk < BK; ++kk) {
            float a[4], b[4];
            #pragma unroll
            for (int r = 0; r < 4; ++r) a[r] = sA[kk][ty * 4 + r];
            #pragma unroll
            for (int c = 0; c < 4; ++c) b[c] = sB[kk][tx * 4 + c];
            #pragma unroll
            for (int r = 0; r < 4; ++r)
                #pragma unroll
                for (int c = 0; c < 4; ++c)
                    acc[r][c] += a[r] * b[c];
        }
        __syncthreads();
    }
    #pragma unroll
    for (int r = 0; r < 4; ++r)
        #pragma unroll
        for (int c = 0; c < 4; ++c)
            C[(size_t)(m0 + ty * 4 + r) * N + n0 + tx * 4 + c] = acc[r][c];
}

// RoPE fp32 -> bf16 (optionally scaled). X laid out [B*S, nh, 128].
__global__ __launch_bounds__(256)
void rope_cast(const float* __restrict__ X, unsigned short* __restrict__ Y,
               const float* __restrict__ cosT, const float* __restrict__ sinT,
               int nh, float scale, int total)
{
    int idx = blockIdx.x * 256 + threadIdx.x;
    if (idx >= total) return;
    int i   = idx & 63;
    int rh  = idx >> 6;          // (b*S+s)*nh + h
    int row = rh / nh;           // b*S + s
    int s   = row & (Ss - 1);
    const float* xp = X + (size_t)rh * HDd;
    float x1 = xp[i];
    float x2 = xp[i + 64];
    float c1 = cosT[s * HDd + i];
    float c2 = cosT[s * HDd + i + 64];
    float s1 = sinT[s * HDd + i];
    float s2 = sinT[s * HDd + i + 64];
    Y[(size_t)rh * HDd + i]      = f2bf((x1 * c1 - x2 * s1) * scale);
    Y[(size_t)rh * HDd + i + 64] = f2bf((x2 * c2 + x1 * s2) * scale);
}

// Vf [B,S,KVH,128] fp32 -> VT [B,KVH,128,S] bf16 (transpose + cast)
__global__ __launch_bounds__(256)
void vt_cast(const float* __restrict__ Vf, unsigned short* __restrict__ VT)
{
    __shared__ float tile[32][33];
    int st = blockIdx.x * 32, dt = blockIdx.y * 32;
    int bk = blockIdx.z;
    int b = bk >> 2, kvh = bk & 3;
    int tx = threadIdx.x & 31, ty = threadIdx.x >> 5;   // 32 x 8
    #pragma unroll
    for (int i = 0; i < 32; i += 8)
        tile[ty + i][tx] = Vf[(((size_t)b * Ss + st + ty + i) * KVHh + kvh) * HDd + dt + tx];
    __syncthreads();
    #pragma unroll
    for (int i = 0; i < 32; i += 8)
        VT[(((size_t)b * KVHh + kvh) * HDd + dt + ty + i) * Ss + st + tx] =
            f2bf(tile[tx][ty + i]);
}

// Flash attention: block = 4 waves; wave w owns q-tile [q0, q0+16) of (b,h).
// Qb pre-scaled by 1/sqrt(128). k-loop over 32-key tiles, causal bound.
__global__ __launch_bounds__(256)
void flash_attn(const unsigned short* __restrict__ Qb,   // [B,S,H,128] bf16
                const unsigned short* __restrict__ Kb,   // [B,S,KVH,128] bf16
                const unsigned short* __restrict__ VT,   // [B,KVH,128,S] bf16
                const float* __restrict__ alibi,         // [B,S,S]
                const float* __restrict__ amask,         // [B,S]
                float* __restrict__ ctx)                 // [B,S,H,128] fp32
{
    __shared__ unsigned short s_p[4][16][56];   // P rows padded to 56 (112B, 16B-aligned)
    const int tid  = threadIdx.x;
    const int wave = tid >> 6;
    const int lane = tid & 63;
    const int m    = lane & 15;
    const int quad = lane >> 4;

    const int qt  = (gridDim.x - 1) - blockIdx.x;  // heavy tiles dispatch first
    const int h   = blockIdx.y;
    const int b   = blockIdx.z;
    const int kvh = h >> 2;
    const int q0  = qt * 64 + wave * 16;

    // Q A-frags: A[m=lane&15][k=quad*8+j], 4 chunks of 32 dims
    bf16x8 qa[4];
    {
        const unsigned short* qrow = Qb + (((size_t)b * Ss + q0 + m) * Hh + h) * HDd;
        #pragma unroll
        for (int c = 0; c < 4; ++c)
            qa[c] = *reinterpret_cast<const bf16x8*>(qrow + c * 32 + quad * 8);
    }

    f32x4 o[8];
    #pragma unroll
    for (int f = 0; f < 8; ++f) o[f] = (f32x4){0.f, 0.f, 0.f, 0.f};
    float mrow[4] = {-1e30f, -1e30f, -1e30f, -1e30f};
    float lrow[4] = {0.f, 0.f, 0.f, 0.f};

    const unsigned short* vt0 = VT + ((size_t)b * KVHh + kvh) * HDd * Ss;
    const float* arow  = alibi + ((size_t)b * Ss + q0 + quad * 4) * Ss;
    const float* amrow = amask + (size_t)b * Ss;

    const int ntiles = (q0 + 16 + 31) >> 5;      // keys 0..q0+15
    for (int kt = 0; kt < ntiles; ++kt) {
        const int k0 = kt * 32;
        // S-tile [16q x 32k] = two C-frags, accumulated over 4 dim-chunks
        f32x4 s0 = {0.f, 0.f, 0.f, 0.f}, s1 = {0.f, 0.f, 0.f, 0.f};
        const unsigned short* krow0 = Kb + (((size_t)b * Ss + k0 + m) * KVHh + kvh) * HDd;
        const unsigned short* krow1 = krow0 + (size_t)16 * KVHh * HDd;
        #pragma unroll
        for (int c = 0; c < 4; ++c) {
            bf16x8 kb0 = *reinterpret_cast<const bf16x8*>(krow0 + c * 32 + quad * 8);
            bf16x8 kb1 = *reinterpret_cast<const bf16x8*>(krow1 + c * 32 + quad * 8);
            s0 = __builtin_amdgcn_mfma_f32_16x16x32_bf16(qa[c], kb0, s0, 0, 0, 0);
            s1 = __builtin_amdgcn_mfma_f32_16x16x32_bf16(qa[c], kb1, s1, 0, 0, 0);
        }
        // bias + causal + online softmax; C/D layout: row=quad*4+r, col=m
        const float am0 = amrow[k0 + m];
        const float am1 = amrow[k0 + 16 + m];
        float alpha[4];
        #pragma unroll
        for (int r = 0; r < 4; ++r) {
            const int qi = q0 + quad * 4 + r;
            float a0 = s0[r] + arow[(size_t)r * Ss + k0 + m] + am0;
            float a1 = s1[r] + arow[(size_t)r * Ss + k0 + 16 + m] + am1;
            a0 = (k0 + m      <= qi) ? a0 : -1e30f;
            a1 = (k0 + 16 + m <= qi) ? a1 : -1e30f;
            float mx = fmaxf(a0, a1);
            mx = fmaxf(mx, __shfl_xor(mx, 1, 64));
            mx = fmaxf(mx, __shfl_xor(mx, 2, 64));
            mx = fmaxf(mx, __shfl_xor(mx, 4, 64));
            mx = fmaxf(mx, __shfl_xor(mx, 8, 64));
            const float mnew = fmaxf(mrow[r], mx);
            alpha[r] = __expf(mrow[r] - mnew);
            mrow[r]  = mnew;
            const float p0 = __expf(a0 - mnew);
            const float p1 = __expf(a1 - mnew);
            float rs = p0 + p1;
            rs += __shfl_xor(rs, 1, 64);
            rs += __shfl_xor(rs, 2, 64);
            rs += __shfl_xor(rs, 4, 64);
            rs += __shfl_xor(rs, 8, 64);
            lrow[r] = lrow[r] * alpha[r] + rs;
            s_p[wave][quad * 4 + r][m]      = f2bf(p0);
            s_p[wave][quad * 4 + r][16 + m] = f2bf(p1);
        }
        #pragma unroll
        for (int f = 0; f < 8; ++f) {
            o[f][0] *= alpha[0];
            o[f][1] *= alpha[1];
            o[f][2] *= alpha[2];
            o[f][3] *= alpha[3];
        }
        // P: C-layout (written above) -> A-layout (read below). Same-wave DS is
        // in-order; wave_barrier pins compiler scheduling.
        __builtin_amdgcn_wave_barrier();
        const bf16x8 pa = *reinterpret_cast<const bf16x8*>(&s_p[wave][m][quad * 8]);
        __builtin_amdgcn_wave_barrier();
        // PV: O[16q x 128d] += P[16x32] @ V[32k x 128d]; B-frag = VT row loads
        #pragma unroll
        for (int f = 0; f < 8; ++f) {
            const bf16x8 vb = *reinterpret_cast<const bf16x8*>(
                vt0 + (size_t)(f * 16 + m) * Ss + k0 + quad * 8);
            o[f] = __builtin_amdgcn_mfma_f32_16x16x32_bf16(pa, vb, o[f], 0, 0, 0);
        }
    }

    float inv[4];
    #pragma unroll
    for (int r = 0; r < 4; ++r) inv[r] = 1.f / lrow[r];
    #pragma unroll
    for (int f = 0; f < 8; ++f)
        #pragma unroll
        for (int r = 0; r < 4; ++r)
            ctx[(((size_t)b * Ss + q0 + quad * 4 + r) * Hh + h) * HDd + f * 16 + m] =
                o[f][r] * inv[r];
}

extern "C" void kernel_launch(void* const* d_in, const int* in_sizes, int n_in,
                              void* d_out, int out_size, void* d_ws, size_t ws_size,
                              hipStream_t stream) {
    const float* hidden = (const float*)d_in[0];
    const float* cosT   = (const float*)d_in[1];
    const float* sinT   = (const float*)d_in[2];
    const float* alibi  = (const float*)d_in[3];
    const float* amask  = (const float*)d_in[4];
    const float* wq     = (const float*)d_in[5];
    const float* wk     = (const float*)d_in[6];
    const float* wv     = (const float*)d_in[7];
    const float* wo     = (const float*)d_in[8];
    float* out = (float*)d_out;

    char* ws = (char*)d_ws;
    float* Qf = (float*)(ws);                              // 33,554,432 B
    float* Kf = (float*)(ws + 33554432);                   //  8,388,608 B
    float* Vf = (float*)(ws + 41943040);                   //  8,388,608 B
    unsigned short* Qb = (unsigned short*)(ws + 50331648); // 16,777,216 B
    unsigned short* Kb = (unsigned short*)(ws + 67108864); //  4,194,304 B
    unsigned short* VT = (unsigned short*)(ws + 71303168); //  4,194,304 B
    float* Cf = Qf;   // ctx aliases Qf (Qf dead after rope_cast)  total 75.5 MB

    int M = Bb * Ss;  // 4096

    gemm_f32<<<dim3(Dd / BN, M / BM), 256, 0, stream>>>(hidden, wq, Qf, M, Dd, Dd);
    gemm_f32<<<dim3((KVHh * HDd) / BN, M / BM), 256, 0, stream>>>(hidden, wk, Kf, M, KVHh * HDd, Dd);
    gemm_f32<<<dim3((KVHh * HDd) / BN, M / BM), 256, 0, stream>>>(hidden, wv, Vf, M, KVHh * HDd, Dd);

    const float scale = 0.08838834764831845f;  // 1/sqrt(128), folded into Qb
    int totQ = Bb * Ss * Hh * 64;
    rope_cast<<<totQ / 256, 256, 0, stream>>>(Qf, Qb, cosT, sinT, Hh, scale, totQ);
    int totK = Bb * Ss * KVHh * 64;
    rope_cast<<<totK / 256, 256, 0, stream>>>(Kf, Kb, cosT, sinT, KVHh, 1.0f, totK);

    vt_cast<<<dim3(Ss / 32, HDd / 32, Bb * KVHh), 256, 0, stream>>>(Vf, VT);

    flash_attn<<<dim3(Ss / 64, Hh, Bb), 256, 0, stream>>>(Qb, Kb, VT, alibi, amask, Cf);

    gemm_f32<<<dim3(Dd / BN, M / BM), 256, 0, stream>>>(Cf, wo, out, M, Dd, Dd);
}

// Round 4
// 808.929 us; speedup vs baseline: 8.8901x; 2.8290x over previous
//
#include <hip/hip_runtime.h>
#include <hip/hip_bf16.h>

#define Bb   2
#define Ss   2048
#define Dd   2048
#define Hh   16
#define KVHh 4
#define HDd  128

typedef __bf16 bf16x8 __attribute__((ext_vector_type(8)));
typedef float f32x4 __attribute__((ext_vector_type(4)));

__device__ __forceinline__ unsigned short f2bf(float f) {
    unsigned u = __float_as_uint(f);
    unsigned r = (u + 0x7FFFu + ((u >> 16) & 1u)) >> 16;   // RNE
    return (unsigned short)r;
}
__device__ __forceinline__ float bfu2f(unsigned short u) {
    return __uint_as_float(((unsigned)u) << 16);
}

// async global->LDS, 16B per lane; lds base must be wave-uniform
#define GLOAD16(g, l) __builtin_amdgcn_global_load_lds( \
    (const __attribute__((address_space(1))) unsigned int*)(g), \
    (__attribute__((address_space(3))) unsigned int*)(l), 16, 0, 0)

// fp32 -> bf16 elementwise, 4 elems/thread
__global__ __launch_bounds__(256)
void cast_bf16(const float* __restrict__ X, unsigned short* __restrict__ Y)
{
    int idx = blockIdx.x * 256 + threadIdx.x;
    float4 v = reinterpret_cast<const float4*>(X)[idx];
    ushort4 o;
    o.x = f2bf(v.x); o.y = f2bf(v.y); o.z = f2bf(v.z); o.w = f2bf(v.w);
    reinterpret_cast<ushort4*>(Y)[idx] = o;
}

// W[K,N] fp32 -> WT[N,K] bf16
__global__ __launch_bounds__(256)
void wt_cast(const float* __restrict__ W, unsigned short* __restrict__ WT,
             int K, int N)
{
    __shared__ float tile[32][33];
    int k0 = blockIdx.x * 32, n0 = blockIdx.y * 32;
    int tx = threadIdx.x & 31, ty = threadIdx.x >> 5;   // 32 x 8
    #pragma unroll
    for (int i = 0; i < 32; i += 8)
        tile[ty + i][tx] = W[(size_t)(k0 + ty + i) * N + n0 + tx];
    __syncthreads();
    #pragma unroll
    for (int i = 0; i < 32; i += 8)
        WT[(size_t)(n0 + ty + i) * K + k0 + tx] = f2bf(tile[tx][ty + i]);
}

// C[M,N] = A[M,K] @ BT[N,K]^T, bf16 in, fp32 accumulate, fp32 or bf16 out.
// 128x128 tile, BK=32, 4 waves (2x2 of 64x64), global_load_lds staging.
template<bool BF16OUT>
__global__ __launch_bounds__(256)
void gemm_bt(const unsigned short* __restrict__ A,
             const unsigned short* __restrict__ BT,
             void* __restrict__ Cv, int M, int N, int K)
{
    __shared__ __align__(16) unsigned short sA[128 * 32];
    __shared__ __align__(16) unsigned short sB[128 * 32];
    const int tid  = threadIdx.x;
    const int wave = tid >> 6;
    const int lane = tid & 63;
    const int m    = lane & 15;
    const int quad = lane >> 4;
    const int wm   = wave >> 1, wn = wave & 1;
    const int m0   = blockIdx.y * 128, n0 = blockIdx.x * 128;

    const int srow = tid >> 2;          // 0..63
    const int skg  = (tid & 3) * 8;     // k-group *8 elems

    f32x4 acc[4][4];
    #pragma unroll
    for (int r = 0; r < 4; ++r)
        #pragma unroll
        for (int c = 0; c < 4; ++c) acc[r][c] = (f32x4){0.f, 0.f, 0.f, 0.f};

    const unsigned short* pa = A  + (size_t)(m0 + srow) * K + skg;
    const unsigned short* pb = BT + (size_t)(n0 + srow) * K + skg;
    unsigned short* la = &sA[wave * 16 * 32];   // wave-uniform LDS base
    unsigned short* lb = &sB[wave * 16 * 32];

    for (int k0 = 0; k0 < K; k0 += 32) {
        GLOAD16(pa + k0, la);
        GLOAD16(pa + (size_t)64 * K + k0, la + 64 * 32);
        GLOAD16(pb + k0, lb);
        GLOAD16(pb + (size_t)64 * K + k0, lb + 64 * 32);
        __syncthreads();
        bf16x8 af[4], bfr[4];
        #pragma unroll
        for (int r = 0; r < 4; ++r)
            af[r] = *reinterpret_cast<const bf16x8*>(
                &sA[(wm * 64 + r * 16 + m) * 32 + quad * 8]);
        #pragma unroll
        for (int c = 0; c < 4; ++c)
            bfr[c] = *reinterpret_cast<const bf16x8*>(
                &sB[(wn * 64 + c * 16 + m) * 32 + quad * 8]);
        #pragma unroll
        for (int r = 0; r < 4; ++r)
            #pragma unroll
            for (int c = 0; c < 4; ++c)
                acc[r][c] = __builtin_amdgcn_mfma_f32_16x16x32_bf16(
                    af[r], bfr[c], acc[r][c], 0, 0, 0);
        __syncthreads();
    }
    // C/D layout: row = quad*4 + e, col = m
    #pragma unroll
    for (int r = 0; r < 4; ++r)
        #pragma unroll
        for (int c = 0; c < 4; ++c)
            #pragma unroll
            for (int e = 0; e < 4; ++e) {
                size_t row = m0 + wm * 64 + r * 16 + quad * 4 + e;
                size_t col = n0 + wn * 64 + c * 16 + m;
                if (BF16OUT)
                    ((unsigned short*)Cv)[row * N + col] = f2bf(acc[r][c][e]);
                else
                    ((float*)Cv)[row * N + col] = acc[r][c][e];
            }
}

// In-place RoPE on bf16 X, rows of `rowstride`, head slice h*128.
__global__ __launch_bounds__(256)
void rope_bf(unsigned short* __restrict__ X, const float* __restrict__ cosT,
             const float* __restrict__ sinT, int nhshift, int rowstride,
             float scale, int total)
{
    int idx = blockIdx.x * 256 + threadIdx.x;
    if (idx >= total) return;
    int i   = idx & 63;
    int rh  = idx >> 6;                  // (b*S+s)*nh + h
    int row = rh >> nhshift;             // b*S + s
    int h   = rh & ((1 << nhshift) - 1);
    int s   = row & (Ss - 1);
    unsigned short* xp = X + (size_t)row * rowstride + h * HDd;
    float x1 = bfu2f(xp[i]);
    float x2 = bfu2f(xp[i + 64]);
    float c1 = cosT[s * HDd + i];
    float c2 = cosT[s * HDd + i + 64];
    float s1 = sinT[s * HDd + i];
    float s2 = sinT[s * HDd + i + 64];
    xp[i]      = f2bf((x1 * c1 - x2 * s1) * scale);
    xp[i + 64] = f2bf((x2 * c2 + x1 * s2) * scale);
}

// V (cols 512.. of KVraw [B*S,1024] bf16) -> VT [B,KVH,128,S] bf16
__global__ __launch_bounds__(256)
void vt_cast_bf(const unsigned short* __restrict__ KV,
                unsigned short* __restrict__ VT)
{
    __shared__ unsigned short tile[32][34];
    int st = blockIdx.x * 32, dt = blockIdx.y * 32;
    int bk = blockIdx.z;
    int b = bk >> 2, kvh = bk & 3;
    int tx = threadIdx.x & 31, ty = threadIdx.x >> 5;   // 32 x 8
    #pragma unroll
    for (int i = 0; i < 32; i += 8)
        tile[ty + i][tx] = KV[(size_t)(b * Ss + st + ty + i) * 1024 + 512 + kvh * HDd + dt + tx];
    __syncthreads();
    #pragma unroll
    for (int i = 0; i < 32; i += 8)
        VT[(((size_t)b * KVHh + kvh) * HDd + dt + ty + i) * Ss + st + tx] =
            tile[tx][ty + i];
}

// Flash attention: block = 4 waves; wave w owns q-tile [q0, q0+16) of (b,h).
// Qb pre-scaled by 1/sqrt(128). K lives in KVraw cols 0..511 (row stride 1024).
__global__ __launch_bounds__(256)
void flash_attn(const unsigned short* __restrict__ Qb,   // [B*S,2048] bf16
                const unsigned short* __restrict__ KVb,  // [B*S,1024] bf16 (K part)
                const unsigned short* __restrict__ VT,   // [B,KVH,128,S] bf16
                const float* __restrict__ alibi,         // [B,S,S]
                const float* __restrict__ amask,         // [B,S]
                unsigned short* __restrict__ ctx)        // [B*S,2048] bf16
{
    __shared__ unsigned short s_p[4][16][56];   // P rows padded to 112B (16B-aligned)
    const int tid  = threadIdx.x;
    const int wave = tid >> 6;
    const int lane = tid & 63;
    const int m    = lane & 15;
    const int quad = lane >> 4;

    const int qt  = (gridDim.x - 1) - blockIdx.x;  // heavy tiles dispatch first
    const int h   = blockIdx.y;
    const int b   = blockIdx.z;
    const int kvh = h >> 2;
    const int q0  = qt * 64 + wave * 16;

    bf16x8 qa[4];
    {
        const unsigned short* qrow = Qb + (size_t)(b * Ss + q0 + m) * Dd + h * HDd;
        #pragma unroll
        for (int c = 0; c < 4; ++c)
            qa[c] = *reinterpret_cast<const bf16x8*>(qrow + c * 32 + quad * 8);
    }

    f32x4 o[8];
    #pragma unroll
    for (int f = 0; f < 8; ++f) o[f] = (f32x4){0.f, 0.f, 0.f, 0.f};
    float mrow[4] = {-1e30f, -1e30f, -1e30f, -1e30f};
    float lrow[4] = {0.f, 0.f, 0.f, 0.f};

    const unsigned short* vt0 = VT + ((size_t)b * KVHh + kvh) * HDd * Ss;
    const float* arow  = alibi + ((size_t)b * Ss + q0 + quad * 4) * Ss;
    const float* amrow = amask + (size_t)b * Ss;

    const int ntiles = (q0 + 16 + 31) >> 5;      // keys 0..q0+15
    for (int kt = 0; kt < ntiles; ++kt) {
        const int k0 = kt * 32;
        f32x4 s0 = {0.f, 0.f, 0.f, 0.f}, s1 = {0.f, 0.f, 0.f, 0.f};
        const unsigned short* krow0 = KVb + (size_t)(b * Ss + k0 + m) * 1024 + kvh * HDd;
        const unsigned short* krow1 = krow0 + (size_t)16 * 1024;
        #pragma unroll
        for (int c = 0; c < 4; ++c) {
            bf16x8 kb0 = *reinterpret_cast<const bf16x8*>(krow0 + c * 32 + quad * 8);
            bf16x8 kb1 = *reinterpret_cast<const bf16x8*>(krow1 + c * 32 + quad * 8);
            s0 = __builtin_amdgcn_mfma_f32_16x16x32_bf16(qa[c], kb0, s0, 0, 0, 0);
            s1 = __builtin_amdgcn_mfma_f32_16x16x32_bf16(qa[c], kb1, s1, 0, 0, 0);
        }
        const float am0 = amrow[k0 + m];
        const float am1 = amrow[k0 + 16 + m];
        float alpha[4];
        #pragma unroll
        for (int r = 0; r < 4; ++r) {
            const int qi = q0 + quad * 4 + r;
            float a0 = s0[r] + arow[(size_t)r * Ss + k0 + m] + am0;
            float a1 = s1[r] + arow[(size_t)r * Ss + k0 + 16 + m] + am1;
            a0 = (k0 + m      <= qi) ? a0 : -1e30f;
            a1 = (k0 + 16 + m <= qi) ? a1 : -1e30f;
            float mx = fmaxf(a0, a1);
            mx = fmaxf(mx, __shfl_xor(mx, 1, 64));
            mx = fmaxf(mx, __shfl_xor(mx, 2, 64));
            mx = fmaxf(mx, __shfl_xor(mx, 4, 64));
            mx = fmaxf(mx, __shfl_xor(mx, 8, 64));
            const float mnew = fmaxf(mrow[r], mx);
            alpha[r] = __expf(mrow[r] - mnew);
            mrow[r]  = mnew;
            const float p0 = __expf(a0 - mnew);
            const float p1 = __expf(a1 - mnew);
            float rs = p0 + p1;
            rs += __shfl_xor(rs, 1, 64);
            rs += __shfl_xor(rs, 2, 64);
            rs += __shfl_xor(rs, 4, 64);
            rs += __shfl_xor(rs, 8, 64);
            lrow[r] = lrow[r] * alpha[r] + rs;
            s_p[wave][quad * 4 + r][m]      = f2bf(p0);
            s_p[wave][quad * 4 + r][16 + m] = f2bf(p1);
        }
        #pragma unroll
        for (int f = 0; f < 8; ++f) {
            o[f][0] *= alpha[0];
            o[f][1] *= alpha[1];
            o[f][2] *= alpha[2];
            o[f][3] *= alpha[3];
        }
        __builtin_amdgcn_wave_barrier();
        const bf16x8 pa = *reinterpret_cast<const bf16x8*>(&s_p[wave][m][quad * 8]);
        __builtin_amdgcn_wave_barrier();
        #pragma unroll
        for (int f = 0; f < 8; ++f) {
            const bf16x8 vb = *reinterpret_cast<const bf16x8*>(
                vt0 + (size_t)(f * 16 + m) * Ss + k0 + quad * 8);
            o[f] = __builtin_amdgcn_mfma_f32_16x16x32_bf16(pa, vb, o[f], 0, 0, 0);
        }
    }

    float inv[4];
    #pragma unroll
    for (int r = 0; r < 4; ++r) inv[r] = 1.f / lrow[r];
    #pragma unroll
    for (int f = 0; f < 8; ++f)
        #pragma unroll
        for (int r = 0; r < 4; ++r)
            ctx[(size_t)(b * Ss + q0 + quad * 4 + r) * Dd + h * HDd + f * 16 + m] =
                f2bf(o[f][r] * inv[r]);
}

extern "C" void kernel_launch(void* const* d_in, const int* in_sizes, int n_in,
                              void* d_out, int out_size, void* d_ws, size_t ws_size,
                              hipStream_t stream) {
    const float* hidden = (const float*)d_in[0];
    const float* cosT   = (const float*)d_in[1];
    const float* sinT   = (const float*)d_in[2];
    const float* alibi  = (const float*)d_in[3];
    const float* amask  = (const float*)d_in[4];
    const float* wq     = (const float*)d_in[5];
    const float* wk     = (const float*)d_in[6];
    const float* wv     = (const float*)d_in[7];
    const float* wo     = (const float*)d_in[8];
    float* out = (float*)d_out;

    char* ws = (char*)d_ws;
    unsigned short* Abf   = (unsigned short*)(ws);              // 16,777,216
    unsigned short* wqT   = (unsigned short*)(ws + 16777216);   //  8,388,608
    unsigned short* kvT   = (unsigned short*)(ws + 25165824);   //  4,194,304
    unsigned short* woT   = (unsigned short*)(ws + 29360128);   //  8,388,608
    unsigned short* Qraw  = (unsigned short*)(ws + 37748736);   // 16,777,216
    unsigned short* KVraw = (unsigned short*)(ws + 54525952);   //  8,388,608
    unsigned short* VT    = (unsigned short*)(ws + 62914560);   //  4,194,304
    unsigned short* Ctx   = (unsigned short*)(ws + 67108864);   // 16,777,216
    // total: 83,886,080 B

    const int M = Bb * Ss;  // 4096

    cast_bf16<<<(M * Dd / 4) / 256, 256, 0, stream>>>(hidden, Abf);
    wt_cast<<<dim3(64, 64), 256, 0, stream>>>(wq, wqT, Dd, Dd);
    wt_cast<<<dim3(64, 16), 256, 0, stream>>>(wk, kvT, Dd, 512);
    wt_cast<<<dim3(64, 16), 256, 0, stream>>>(wv, kvT + (size_t)512 * Dd, Dd, 512);
    wt_cast<<<dim3(64, 64), 256, 0, stream>>>(wo, woT, Dd, Dd);

    gemm_bt<true><<<dim3(Dd / 128, M / 128), 256, 0, stream>>>(Abf, wqT, Qraw, M, Dd, Dd);
    gemm_bt<true><<<dim3(1024 / 128, M / 128), 256, 0, stream>>>(Abf, kvT, KVraw, M, 1024, Dd);

    const float scale = 0.08838834764831845f;  // 1/sqrt(128), folded into Q
    int totQ = Bb * Ss * Hh * 64;
    rope_bf<<<totQ / 256, 256, 0, stream>>>(Qraw, cosT, sinT, 4, Dd, scale, totQ);
    int totK = Bb * Ss * KVHh * 64;
    rope_bf<<<totK / 256, 256, 0, stream>>>(KVraw, cosT, sinT, 2, 1024, 1.0f, totK);

    vt_cast_bf<<<dim3(Ss / 32, HDd / 32, Bb * KVHh), 256, 0, stream>>>(KVraw, VT);

    flash_attn<<<dim3(Ss / 64, Hh, Bb), 256, 0, stream>>>(Qraw, KVraw, VT, alibi, amask, Ctx);

    gemm_bt<false><<<dim3(Dd / 128, M / 128), 256, 0, stream>>>(Ctx, woT, out, M, Dd, Dd);
}

// Round 5
// 681.446 us; speedup vs baseline: 10.5532x; 1.1871x over previous
//
#include <hip/hip_runtime.h>
#include <hip/hip_bf16.h>

#define Bb   2
#define Ss   2048
#define Dd   2048
#define Hh   16
#define KVHh 4
#define HDd  128

typedef __bf16 bf16x8 __attribute__((ext_vector_type(8)));
typedef float f32x4 __attribute__((ext_vector_type(4)));

__device__ __forceinline__ unsigned short f2bf(float f) {
    unsigned u = __float_as_uint(f);
    unsigned r = (u + 0x7FFFu + ((u >> 16) & 1u)) >> 16;   // RNE
    return (unsigned short)r;
}
__device__ __forceinline__ float bfu2f(unsigned short u) {
    return __uint_as_float(((unsigned)u) << 16);
}

// async global->LDS, 16B per lane; lds base must be wave-uniform
#define GLOAD16(g, l) __builtin_amdgcn_global_load_lds( \
    (const __attribute__((address_space(1))) unsigned int*)(g), \
    (__attribute__((address_space(3))) unsigned int*)(l), 16, 0, 0)

// fp32 -> bf16 elementwise, 4 elems/thread
__global__ __launch_bounds__(256)
void cast_bf16(const float* __restrict__ X, unsigned short* __restrict__ Y)
{
    int idx = blockIdx.x * 256 + threadIdx.x;
    float4 v = reinterpret_cast<const float4*>(X)[idx];
    ushort4 o;
    o.x = f2bf(v.x); o.y = f2bf(v.y); o.z = f2bf(v.z); o.w = f2bf(v.w);
    reinterpret_cast<ushort4*>(Y)[idx] = o;
}

// W[K,N] fp32 -> WT[N,K] bf16
__global__ __launch_bounds__(256)
void wt_cast(const float* __restrict__ W, unsigned short* __restrict__ WT,
             int K, int N)
{
    __shared__ float tile[32][33];
    int k0 = blockIdx.x * 32, n0 = blockIdx.y * 32;
    int tx = threadIdx.x & 31, ty = threadIdx.x >> 5;   // 32 x 8
    #pragma unroll
    for (int i = 0; i < 32; i += 8)
        tile[ty + i][tx] = W[(size_t)(k0 + ty + i) * N + n0 + tx];
    __syncthreads();
    #pragma unroll
    for (int i = 0; i < 32; i += 8)
        WT[(size_t)(n0 + ty + i) * K + k0 + tx] = f2bf(tile[tx][ty + i]);
}

// C[M,N] = A[M,K] @ BT[N,K]^T, bf16 in, fp32 accumulate, fp32 or bf16 out.
// 128x128 tile, BK=32, 4 waves (2x2 of 64x64), global_load_lds staging.
template<bool BF16OUT>
__global__ __launch_bounds__(256)
void gemm_bt(const unsigned short* __restrict__ A,
             const unsigned short* __restrict__ BT,
             void* __restrict__ Cv, int M, int N, int K)
{
    __shared__ __align__(16) unsigned short sA[128 * 32];
    __shared__ __align__(16) unsigned short sB[128 * 32];
    const int tid  = threadIdx.x;
    const int wave = tid >> 6;
    const int lane = tid & 63;
    const int m    = lane & 15;
    const int quad = lane >> 4;
    const int wm   = wave >> 1, wn = wave & 1;
    const int m0   = blockIdx.y * 128, n0 = blockIdx.x * 128;

    const int srow = tid >> 2;          // 0..63
    const int skg  = (tid & 3) * 8;     // k-group *8 elems

    f32x4 acc[4][4];
    #pragma unroll
    for (int r = 0; r < 4; ++r)
        #pragma unroll
        for (int c = 0; c < 4; ++c) acc[r][c] = (f32x4){0.f, 0.f, 0.f, 0.f};

    const unsigned short* pa = A  + (size_t)(m0 + srow) * K + skg;
    const unsigned short* pb = BT + (size_t)(n0 + srow) * K + skg;
    unsigned short* la = &sA[wave * 16 * 32];   // wave-uniform LDS base
    unsigned short* lb = &sB[wave * 16 * 32];

    for (int k0 = 0; k0 < K; k0 += 32) {
        GLOAD16(pa + k0, la);
        GLOAD16(pa + (size_t)64 * K + k0, la + 64 * 32);
        GLOAD16(pb + k0, lb);
        GLOAD16(pb + (size_t)64 * K + k0, lb + 64 * 32);
        __syncthreads();
        bf16x8 af[4], bfr[4];
        #pragma unroll
        for (int r = 0; r < 4; ++r)
            af[r] = *reinterpret_cast<const bf16x8*>(
                &sA[(wm * 64 + r * 16 + m) * 32 + quad * 8]);
        #pragma unroll
        for (int c = 0; c < 4; ++c)
            bfr[c] = *reinterpret_cast<const bf16x8*>(
                &sB[(wn * 64 + c * 16 + m) * 32 + quad * 8]);
        #pragma unroll
        for (int r = 0; r < 4; ++r)
            #pragma unroll
            for (int c = 0; c < 4; ++c)
                acc[r][c] = __builtin_amdgcn_mfma_f32_16x16x32_bf16(
                    af[r], bfr[c], acc[r][c], 0, 0, 0);
        __syncthreads();
    }
    // C/D layout: row = quad*4 + e, col = m
    #pragma unroll
    for (int r = 0; r < 4; ++r)
        #pragma unroll
        for (int c = 0; c < 4; ++c)
            #pragma unroll
            for (int e = 0; e < 4; ++e) {
                size_t row = m0 + wm * 64 + r * 16 + quad * 4 + e;
                size_t col = n0 + wn * 64 + c * 16 + m;
                if (BF16OUT)
                    ((unsigned short*)Cv)[row * N + col] = f2bf(acc[r][c][e]);
                else
                    ((float*)Cv)[row * N + col] = acc[r][c][e];
            }
}

// In-place RoPE on bf16 X, rows of `rowstride`, head slice h*128.
__global__ __launch_bounds__(256)
void rope_bf(unsigned short* __restrict__ X, const float* __restrict__ cosT,
             const float* __restrict__ sinT, int nhshift, int rowstride,
             float scale, int total)
{
    int idx = blockIdx.x * 256 + threadIdx.x;
    if (idx >= total) return;
    int i   = idx & 63;
    int rh  = idx >> 6;                  // (b*S+s)*nh + h
    int row = rh >> nhshift;             // b*S + s
    int h   = rh & ((1 << nhshift) - 1);
    int s   = row & (Ss - 1);
    unsigned short* xp = X + (size_t)row * rowstride + h * HDd;
    float x1 = bfu2f(xp[i]);
    float x2 = bfu2f(xp[i + 64]);
    float c1 = cosT[s * HDd + i];
    float c2 = cosT[s * HDd + i + 64];
    float s1 = sinT[s * HDd + i];
    float s2 = sinT[s * HDd + i + 64];
    xp[i]      = f2bf((x1 * c1 - x2 * s1) * scale);
    xp[i + 64] = f2bf((x2 * c2 + x1 * s2) * scale);
}

// V (cols 512.. of KVraw [B*S,1024] bf16) -> VT [B,KVH,128,S] bf16
__global__ __launch_bounds__(256)
void vt_cast_bf(const unsigned short* __restrict__ KV,
                unsigned short* __restrict__ VT)
{
    __shared__ unsigned short tile[32][34];
    int st = blockIdx.x * 32, dt = blockIdx.y * 32;
    int bk = blockIdx.z;
    int b = bk >> 2, kvh = bk & 3;
    int tx = threadIdx.x & 31, ty = threadIdx.x >> 5;   // 32 x 8
    #pragma unroll
    for (int i = 0; i < 32; i += 8)
        tile[ty + i][tx] = KV[(size_t)(b * Ss + st + ty + i) * 1024 + 512 + kvh * HDd + dt + tx];
    __syncthreads();
    #pragma unroll
    for (int i = 0; i < 32; i += 8)
        VT[(((size_t)b * KVHh + kvh) * HDd + dt + ty + i) * Ss + st + tx] =
            tile[tx][ty + i];
}

// Flash attention, max-free softmax (scores bounded; exp sums << fp32 range).
// One wave per block; wave owns q-tile [q0, q0+16). Heavy tiles dispatch first.
// Per k-tile chain: prefetch V/alibi -> QK MFMA -> exp -> LDS P-transpose -> PV.
__global__ __launch_bounds__(64)
void flash_attn(const unsigned short* __restrict__ Qb,   // [B*S,2048] bf16
                const unsigned short* __restrict__ KVb,  // [B*S,1024] bf16 (K part)
                const unsigned short* __restrict__ VT,   // [B,KVH,128,S] bf16
                const float* __restrict__ alibi,         // [B,S,S]
                const float* __restrict__ amask,         // [B,S]
                unsigned short* __restrict__ ctx)        // [B*S,2048] bf16
{
    __shared__ unsigned short s_p[16][56];   // P rows padded to 112B (16B-aligned)
    const int lane = threadIdx.x;
    const int m    = lane & 15;
    const int quad = lane >> 4;

    const int qt  = (gridDim.x - 1) - blockIdx.x;  // heavy tiles dispatch first
    const int h   = blockIdx.y;
    const int b   = blockIdx.z;
    const int kvh = h >> 2;
    const int q0  = qt * 16;

    bf16x8 qa[4];
    {
        const unsigned short* qrow = Qb + (size_t)(b * Ss + q0 + m) * Dd + h * HDd;
        #pragma unroll
        for (int c = 0; c < 4; ++c)
            qa[c] = *reinterpret_cast<const bf16x8*>(qrow + c * 32 + quad * 8);
    }

    f32x4 o[8];
    #pragma unroll
    for (int f = 0; f < 8; ++f) o[f] = (f32x4){0.f, 0.f, 0.f, 0.f};
    float lrow[4] = {0.f, 0.f, 0.f, 0.f};   // per-lane partial sums; reduced once at end

    const unsigned short* vt0 = VT + ((size_t)b * KVHh + kvh) * HDd * Ss;
    const float* arow  = alibi + ((size_t)b * Ss + q0 + quad * 4) * Ss;
    const float* amrow = amask + (size_t)b * Ss;

    const int ntiles = (q0 + 47) >> 5;      // keys 0..q0+15
    for (int kt = 0; kt < ntiles; ++kt) {
        const int k0 = kt * 32;

        // prefetch everything that doesn't depend on QK: V frags, alibi, mask
        bf16x8 vb[8];
        #pragma unroll
        for (int f = 0; f < 8; ++f)
            vb[f] = *reinterpret_cast<const bf16x8*>(
                vt0 + (size_t)(f * 16 + m) * Ss + k0 + quad * 8);
        float al0[4], al1[4];
        #pragma unroll
        for (int r = 0; r < 4; ++r) {
            al0[r] = arow[(size_t)r * Ss + k0 + m];
            al1[r] = arow[(size_t)r * Ss + k0 + 16 + m];
        }
        const float am0 = amrow[k0 + m];
        const float am1 = amrow[k0 + 16 + m];

        // QK^T for 32 keys
        f32x4 s0 = {0.f, 0.f, 0.f, 0.f}, s1 = {0.f, 0.f, 0.f, 0.f};
        const unsigned short* krow0 = KVb + (size_t)(b * Ss + k0 + m) * 1024 + kvh * HDd;
        const unsigned short* krow1 = krow0 + (size_t)16 * 1024;
        #pragma unroll
        for (int c = 0; c < 4; ++c) {
            bf16x8 kb0 = *reinterpret_cast<const bf16x8*>(krow0 + c * 32 + quad * 8);
            bf16x8 kb1 = *reinterpret_cast<const bf16x8*>(krow1 + c * 32 + quad * 8);
            s0 = __builtin_amdgcn_mfma_f32_16x16x32_bf16(qa[c], kb0, s0, 0, 0, 0);
            s1 = __builtin_amdgcn_mfma_f32_16x16x32_bf16(qa[c], kb1, s1, 0, 0, 0);
        }

        // max-free softmax: p = exp(s + bias); no cross-lane work in the loop
        #pragma unroll
        for (int r = 0; r < 4; ++r) {
            const int qi = q0 + quad * 4 + r;
            float a0 = s0[r] + al0[r] + am0;
            float a1 = s1[r] + al1[r] + am1;
            a0 = (k0 + m      <= qi) ? a0 : -1e30f;
            a1 = (k0 + 16 + m <= qi) ? a1 : -1e30f;
            const float p0 = __expf(a0);
            const float p1 = __expf(a1);
            lrow[r] += p0 + p1;
            s_p[quad * 4 + r][m]      = f2bf(p0);
            s_p[quad * 4 + r][16 + m] = f2bf(p1);
        }
        // P: C-layout -> A-layout via LDS (same-wave DS is in-order; barriers
        // pin compiler ordering only — vb loads above stay hoisted)
        __builtin_amdgcn_wave_barrier();
        const bf16x8 pa = *reinterpret_cast<const bf16x8*>(&s_p[m][quad * 8]);
        __builtin_amdgcn_wave_barrier();
        #pragma unroll
        for (int f = 0; f < 8; ++f)
            o[f] = __builtin_amdgcn_mfma_f32_16x16x32_bf16(pa, vb[f], o[f], 0, 0, 0);
    }

    // reduce l across the 16 columns held by lanes of each quad-row group
    float inv[4];
    #pragma unroll
    for (int r = 0; r < 4; ++r) {
        float l = lrow[r];
        l += __shfl_xor(l, 1, 64);
        l += __shfl_xor(l, 2, 64);
        l += __shfl_xor(l, 4, 64);
        l += __shfl_xor(l, 8, 64);
        inv[r] = 1.f / l;
    }
    #pragma unroll
    for (int f = 0; f < 8; ++f)
        #pragma unroll
        for (int r = 0; r < 4; ++r)
            ctx[(size_t)(b * Ss + q0 + quad * 4 + r) * Dd + h * HDd + f * 16 + m] =
                f2bf(o[f][r] * inv[r]);
}

extern "C" void kernel_launch(void* const* d_in, const int* in_sizes, int n_in,
                              void* d_out, int out_size, void* d_ws, size_t ws_size,
                              hipStream_t stream) {
    const float* hidden = (const float*)d_in[0];
    const float* cosT   = (const float*)d_in[1];
    const float* sinT   = (const float*)d_in[2];
    const float* alibi  = (const float*)d_in[3];
    const float* amask  = (const float*)d_in[4];
    const float* wq     = (const float*)d_in[5];
    const float* wk     = (const float*)d_in[6];
    const float* wv     = (const float*)d_in[7];
    const float* wo     = (const float*)d_in[8];
    float* out = (float*)d_out;

    char* ws = (char*)d_ws;
    unsigned short* Abf   = (unsigned short*)(ws);              // 16,777,216
    unsigned short* wqT   = (unsigned short*)(ws + 16777216);   //  8,388,608
    unsigned short* kvT   = (unsigned short*)(ws + 25165824);   //  4,194,304
    unsigned short* woT   = (unsigned short*)(ws + 29360128);   //  8,388,608
    unsigned short* Qraw  = (unsigned short*)(ws + 37748736);   // 16,777,216
    unsigned short* KVraw = (unsigned short*)(ws + 54525952);   //  8,388,608
    unsigned short* VT    = (unsigned short*)(ws + 62914560);   //  4,194,304
    unsigned short* Ctx   = (unsigned short*)(ws + 67108864);   // 16,777,216
    // total: 83,886,080 B

    const int M = Bb * Ss;  // 4096

    cast_bf16<<<(M * Dd / 4) / 256, 256, 0, stream>>>(hidden, Abf);
    wt_cast<<<dim3(64, 64), 256, 0, stream>>>(wq, wqT, Dd, Dd);
    wt_cast<<<dim3(64, 16), 256, 0, stream>>>(wk, kvT, Dd, 512);
    wt_cast<<<dim3(64, 16), 256, 0, stream>>>(wv, kvT + (size_t)512 * Dd, Dd, 512);
    wt_cast<<<dim3(64, 64), 256, 0, stream>>>(wo, woT, Dd, Dd);

    gemm_bt<true><<<dim3(Dd / 128, M / 128), 256, 0, stream>>>(Abf, wqT, Qraw, M, Dd, Dd);
    gemm_bt<true><<<dim3(1024 / 128, M / 128), 256, 0, stream>>>(Abf, kvT, KVraw, M, 1024, Dd);

    const float scale = 0.08838834764831845f;  // 1/sqrt(128), folded into Q
    int totQ = Bb * Ss * Hh * 64;
    rope_bf<<<totQ / 256, 256, 0, stream>>>(Qraw, cosT, sinT, 4, Dd, scale, totQ);
    int totK = Bb * Ss * KVHh * 64;
    rope_bf<<<totK / 256, 256, 0, stream>>>(KVraw, cosT, sinT, 2, 1024, 1.0f, totK);

    vt_cast_bf<<<dim3(Ss / 32, HDd / 32, Bb * KVHh), 256, 0, stream>>>(KVraw, VT);

    flash_attn<<<dim3(Ss / 16, Hh, Bb), 64, 0, stream>>>(Qraw, KVraw, VT, alibi, amask, Ctx);

    gemm_bt<false><<<dim3(Dd / 128, M / 128), 256, 0, stream>>>(Ctx, woT, out, M, Dd, Dd);
}

// Round 6
// 572.250 us; speedup vs baseline: 12.5670x; 1.1908x over previous
//
#include <hip/hip_runtime.h>
#include <hip/hip_bf16.h>

#define Bb   2
#define Ss   2048
#define Dd   2048
#define Hh   16
#define KVHh 4
#define HDd  128

typedef __bf16 bf16x8 __attribute__((ext_vector_type(8)));
typedef float f32x4 __attribute__((ext_vector_type(4)));

__device__ __forceinline__ unsigned short f2bf(float f) {
    unsigned u = __float_as_uint(f);
    unsigned r = (u + 0x7FFFu + ((u >> 16) & 1u)) >> 16;   // RNE
    return (unsigned short)r;
}
__device__ __forceinline__ float bfu2f(unsigned short u) {
    return __uint_as_float(((unsigned)u) << 16);
}

// async global->LDS, 16B per lane; lds base must be wave-uniform
#define GLOAD16(g, l) __builtin_amdgcn_global_load_lds( \
    (const __attribute__((address_space(1))) unsigned int*)(g), \
    (__attribute__((address_space(3))) unsigned int*)(l), 16, 0, 0)

// fp32 -> bf16 elementwise, 4 elems/thread
__global__ __launch_bounds__(256)
void cast_bf16(const float* __restrict__ X, unsigned short* __restrict__ Y)
{
    int idx = blockIdx.x * 256 + threadIdx.x;
    float4 v = reinterpret_cast<const float4*>(X)[idx];
    ushort4 o;
    o.x = f2bf(v.x); o.y = f2bf(v.y); o.z = f2bf(v.z); o.w = f2bf(v.w);
    reinterpret_cast<ushort4*>(Y)[idx] = o;
}

// W[K,N] fp32 -> WT[N,K] bf16
__global__ __launch_bounds__(256)
void wt_cast(const float* __restrict__ W, unsigned short* __restrict__ WT,
             int K, int N)
{
    __shared__ float tile[32][33];
    int k0 = blockIdx.x * 32, n0 = blockIdx.y * 32;
    int tx = threadIdx.x & 31, ty = threadIdx.x >> 5;   // 32 x 8
    #pragma unroll
    for (int i = 0; i < 32; i += 8)
        tile[ty + i][tx] = W[(size_t)(k0 + ty + i) * N + n0 + tx];
    __syncthreads();
    #pragma unroll
    for (int i = 0; i < 32; i += 8)
        WT[(size_t)(n0 + ty + i) * K + k0 + tx] = f2bf(tile[tx][ty + i]);
}

// C[M,N] = A[M,K] @ BT[N,K]^T, bf16 in, fp32 accumulate, fp32 or bf16 out.
// 128x128 tile, BK=32, 4 waves (2x2 of 64x64), global_load_lds staging.
template<bool BF16OUT>
__global__ __launch_bounds__(256)
void gemm_bt(const unsigned short* __restrict__ A,
             const unsigned short* __restrict__ BT,
             void* __restrict__ Cv, int M, int N, int K)
{
    __shared__ __align__(16) unsigned short sA[128 * 32];
    __shared__ __align__(16) unsigned short sB[128 * 32];
    const int tid  = threadIdx.x;
    const int wave = tid >> 6;
    const int lane = tid & 63;
    const int m    = lane & 15;
    const int quad = lane >> 4;
    const int wm   = wave >> 1, wn = wave & 1;
    const int m0   = blockIdx.y * 128, n0 = blockIdx.x * 128;

    const int srow = tid >> 2;          // 0..63
    const int skg  = (tid & 3) * 8;     // k-group *8 elems

    f32x4 acc[4][4];
    #pragma unroll
    for (int r = 0; r < 4; ++r)
        #pragma unroll
        for (int c = 0; c < 4; ++c) acc[r][c] = (f32x4){0.f, 0.f, 0.f, 0.f};

    const unsigned short* pa = A  + (size_t)(m0 + srow) * K + skg;
    const unsigned short* pb = BT + (size_t)(n0 + srow) * K + skg;
    unsigned short* la = &sA[wave * 16 * 32];   // wave-uniform LDS base
    unsigned short* lb = &sB[wave * 16 * 32];

    for (int k0 = 0; k0 < K; k0 += 32) {
        GLOAD16(pa + k0, la);
        GLOAD16(pa + (size_t)64 * K + k0, la + 64 * 32);
        GLOAD16(pb + k0, lb);
        GLOAD16(pb + (size_t)64 * K + k0, lb + 64 * 32);
        __syncthreads();
        bf16x8 af[4], bfr[4];
        #pragma unroll
        for (int r = 0; r < 4; ++r)
            af[r] = *reinterpret_cast<const bf16x8*>(
                &sA[(wm * 64 + r * 16 + m) * 32 + quad * 8]);
        #pragma unroll
        for (int c = 0; c < 4; ++c)
            bfr[c] = *reinterpret_cast<const bf16x8*>(
                &sB[(wn * 64 + c * 16 + m) * 32 + quad * 8]);
        #pragma unroll
        for (int r = 0; r < 4; ++r)
            #pragma unroll
            for (int c = 0; c < 4; ++c)
                acc[r][c] = __builtin_amdgcn_mfma_f32_16x16x32_bf16(
                    af[r], bfr[c], acc[r][c], 0, 0, 0);
        __syncthreads();
    }
    // C/D layout: row = quad*4 + e, col = m
    #pragma unroll
    for (int r = 0; r < 4; ++r)
        #pragma unroll
        for (int c = 0; c < 4; ++c)
            #pragma unroll
            for (int e = 0; e < 4; ++e) {
                size_t row = m0 + wm * 64 + r * 16 + quad * 4 + e;
                size_t col = n0 + wn * 64 + c * 16 + m;
                if (BF16OUT)
                    ((unsigned short*)Cv)[row * N + col] = f2bf(acc[r][c][e]);
                else
                    ((float*)Cv)[row * N + col] = acc[r][c][e];
            }
}

// In-place RoPE on bf16 X, rows of `rowstride`, head slice h*128.
__global__ __launch_bounds__(256)
void rope_bf(unsigned short* __restrict__ X, const float* __restrict__ cosT,
             const float* __restrict__ sinT, int nhshift, int rowstride,
             float scale, int total)
{
    int idx = blockIdx.x * 256 + threadIdx.x;
    if (idx >= total) return;
    int i   = idx & 63;
    int rh  = idx >> 6;                  // (b*S+s)*nh + h
    int row = rh >> nhshift;             // b*S + s
    int h   = rh & ((1 << nhshift) - 1);
    int s   = row & (Ss - 1);
    unsigned short* xp = X + (size_t)row * rowstride + h * HDd;
    float x1 = bfu2f(xp[i]);
    float x2 = bfu2f(xp[i + 64]);
    float c1 = cosT[s * HDd + i];
    float c2 = cosT[s * HDd + i + 64];
    float s1 = sinT[s * HDd + i];
    float s2 = sinT[s * HDd + i + 64];
    xp[i]      = f2bf((x1 * c1 - x2 * s1) * scale);
    xp[i + 64] = f2bf((x2 * c2 + x1 * s2) * scale);
}

// V (cols 512.. of KVraw [B*S,1024] bf16) -> VT [B,KVH,128,S] bf16
__global__ __launch_bounds__(256)
void vt_cast_bf(const unsigned short* __restrict__ KV,
                unsigned short* __restrict__ VT)
{
    __shared__ unsigned short tile[32][34];
    int st = blockIdx.x * 32, dt = blockIdx.y * 32;
    int bk = blockIdx.z;
    int b = bk >> 2, kvh = bk & 3;
    int tx = threadIdx.x & 31, ty = threadIdx.x >> 5;   // 32 x 8
    #pragma unroll
    for (int i = 0; i < 32; i += 8)
        tile[ty + i][tx] = KV[(size_t)(b * Ss + st + ty + i) * 1024 + 512 + kvh * HDd + dt + tx];
    __syncthreads();
    #pragma unroll
    for (int i = 0; i < 32; i += 8)
        VT[(((size_t)b * KVHh + kvh) * HDd + dt + ty + i) * Ss + st + tx] =
            tile[tx][ty + i];
}

// Flash attention, max-free softmax (scores bounded; exp sums << fp32 range).
// One wave per block, __launch_bounds__(64,1) so ALL per-tile loads stay in
// flight (round-5 fix: VGPR=76 had serialized them). Each wave processes the
// balanced q-tile pair {qt, 127-qt} (~65 k-tiles each -> no causal tail).
// Per k-tile issue order: K first, alibi, V last -> in-order completion gives
// QK/exp/PV progressively finer vmcnt waits.
__global__ __launch_bounds__(64, 1)
void flash_attn(const unsigned short* __restrict__ Qb,   // [B*S,2048] bf16
                const unsigned short* __restrict__ KVb,  // [B*S,1024] bf16 (K part)
                const unsigned short* __restrict__ VT,   // [B,KVH,128,S] bf16
                const float* __restrict__ alibi,         // [B,S,S]
                const float* __restrict__ amask,         // [B,S]
                unsigned short* __restrict__ ctx)        // [B*S,2048] bf16
{
    __shared__ unsigned short s_p[16][56];   // P rows padded to 112B (16B-aligned)
    const int lane = threadIdx.x;
    const int m    = lane & 15;
    const int quad = lane >> 4;

    const int h   = blockIdx.y;
    const int b   = blockIdx.z;
    const int kvh = h >> 2;

    const unsigned short* vt0 = VT + ((size_t)b * KVHh + kvh) * HDd * Ss;
    const float* amrow = amask + (size_t)b * Ss;

    const int qts[2] = { (int)blockIdx.x, 127 - (int)blockIdx.x };

    #pragma unroll 1
    for (int pi = 0; pi < 2; ++pi) {
        const int q0 = qts[pi] * 16;

        bf16x8 qa[4];
        {
            const unsigned short* qrow = Qb + (size_t)(b * Ss + q0 + m) * Dd + h * HDd;
            #pragma unroll
            for (int c = 0; c < 4; ++c)
                qa[c] = *reinterpret_cast<const bf16x8*>(qrow + c * 32 + quad * 8);
        }

        f32x4 o[8];
        #pragma unroll
        for (int f = 0; f < 8; ++f) o[f] = (f32x4){0.f, 0.f, 0.f, 0.f};
        float lrow[4] = {0.f, 0.f, 0.f, 0.f};

        const float* arow = alibi + ((size_t)b * Ss + q0 + quad * 4) * Ss;

        const int ntiles = (q0 + 47) >> 5;      // keys 0..q0+15
        for (int kt = 0; kt < ntiles; ++kt) {
            const int k0 = kt * 32;

            // --- issue K loads first (QK waits only on these) ---
            bf16x8 kb0[4], kb1[4];
            {
                const unsigned short* krow0 =
                    KVb + (size_t)(b * Ss + k0 + m) * 1024 + kvh * HDd;
                const unsigned short* krow1 = krow0 + (size_t)16 * 1024;
                #pragma unroll
                for (int c = 0; c < 4; ++c) {
                    kb0[c] = *reinterpret_cast<const bf16x8*>(krow0 + c * 32 + quad * 8);
                    kb1[c] = *reinterpret_cast<const bf16x8*>(krow1 + c * 32 + quad * 8);
                }
            }
            // --- then alibi/mask (exp waits on these) ---
            float al0[4], al1[4];
            #pragma unroll
            for (int r = 0; r < 4; ++r) {
                al0[r] = arow[(size_t)r * Ss + k0 + m];
                al1[r] = arow[(size_t)r * Ss + k0 + 16 + m];
            }
            const float am0 = amrow[k0 + m];
            const float am1 = amrow[k0 + 16 + m];
            // --- V last (only PV waits on these) ---
            bf16x8 vb[8];
            #pragma unroll
            for (int f = 0; f < 8; ++f)
                vb[f] = *reinterpret_cast<const bf16x8*>(
                    vt0 + (size_t)(f * 16 + m) * Ss + k0 + quad * 8);

            // QK^T for 32 keys
            f32x4 s0 = {0.f, 0.f, 0.f, 0.f}, s1 = {0.f, 0.f, 0.f, 0.f};
            #pragma unroll
            for (int c = 0; c < 4; ++c) {
                s0 = __builtin_amdgcn_mfma_f32_16x16x32_bf16(qa[c], kb0[c], s0, 0, 0, 0);
                s1 = __builtin_amdgcn_mfma_f32_16x16x32_bf16(qa[c], kb1[c], s1, 0, 0, 0);
            }

            // max-free softmax: p = exp(s + bias); no cross-lane work in loop
            #pragma unroll
            for (int r = 0; r < 4; ++r) {
                const int qi = q0 + quad * 4 + r;
                float a0 = s0[r] + al0[r] + am0;
                float a1 = s1[r] + al1[r] + am1;
                a0 = (k0 + m      <= qi) ? a0 : -1e30f;
                a1 = (k0 + 16 + m <= qi) ? a1 : -1e30f;
                const float p0 = __expf(a0);
                const float p1 = __expf(a1);
                lrow[r] += p0 + p1;
                s_p[quad * 4 + r][m]      = f2bf(p0);
                s_p[quad * 4 + r][16 + m] = f2bf(p1);
            }
            // P: C-layout -> A-layout via LDS (same-wave DS is in-order)
            __builtin_amdgcn_wave_barrier();
            const bf16x8 pa = *reinterpret_cast<const bf16x8*>(&s_p[m][quad * 8]);
            __builtin_amdgcn_wave_barrier();
            #pragma unroll
            for (int f = 0; f < 8; ++f)
                o[f] = __builtin_amdgcn_mfma_f32_16x16x32_bf16(pa, vb[f], o[f], 0, 0, 0);
        }

        // reduce l across the 16 columns held by lanes of each quad-row group
        float inv[4];
        #pragma unroll
        for (int r = 0; r < 4; ++r) {
            float l = lrow[r];
            l += __shfl_xor(l, 1, 64);
            l += __shfl_xor(l, 2, 64);
            l += __shfl_xor(l, 4, 64);
            l += __shfl_xor(l, 8, 64);
            inv[r] = 1.f / l;
        }
        #pragma unroll
        for (int f = 0; f < 8; ++f)
            #pragma unroll
            for (int r = 0; r < 4; ++r)
                ctx[(size_t)(b * Ss + q0 + quad * 4 + r) * Dd + h * HDd + f * 16 + m] =
                    f2bf(o[f][r] * inv[r]);
    }
}

extern "C" void kernel_launch(void* const* d_in, const int* in_sizes, int n_in,
                              void* d_out, int out_size, void* d_ws, size_t ws_size,
                              hipStream_t stream) {
    const float* hidden = (const float*)d_in[0];
    const float* cosT   = (const float*)d_in[1];
    const float* sinT   = (const float*)d_in[2];
    const float* alibi  = (const float*)d_in[3];
    const float* amask  = (const float*)d_in[4];
    const float* wq     = (const float*)d_in[5];
    const float* wk     = (const float*)d_in[6];
    const float* wv     = (const float*)d_in[7];
    const float* wo     = (const float*)d_in[8];
    float* out = (float*)d_out;

    char* ws = (char*)d_ws;
    unsigned short* Abf   = (unsigned short*)(ws);              // 16,777,216
    unsigned short* wqT   = (unsigned short*)(ws + 16777216);   //  8,388,608
    unsigned short* kvT   = (unsigned short*)(ws + 25165824);   //  4,194,304
    unsigned short* woT   = (unsigned short*)(ws + 29360128);   //  8,388,608
    unsigned short* Qraw  = (unsigned short*)(ws + 37748736);   // 16,777,216
    unsigned short* KVraw = (unsigned short*)(ws + 54525952);   //  8,388,608
    unsigned short* VT    = (unsigned short*)(ws + 62914560);   //  4,194,304
    unsigned short* Ctx   = (unsigned short*)(ws + 67108864);   // 16,777,216
    // total: 83,886,080 B

    const int M = Bb * Ss;  // 4096

    cast_bf16<<<(M * Dd / 4) / 256, 256, 0, stream>>>(hidden, Abf);
    wt_cast<<<dim3(64, 64), 256, 0, stream>>>(wq, wqT, Dd, Dd);
    wt_cast<<<dim3(64, 16), 256, 0, stream>>>(wk, kvT, Dd, 512);
    wt_cast<<<dim3(64, 16), 256, 0, stream>>>(wv, kvT + (size_t)512 * Dd, Dd, 512);
    wt_cast<<<dim3(64, 64), 256, 0, stream>>>(wo, woT, Dd, Dd);

    gemm_bt<true><<<dim3(Dd / 128, M / 128), 256, 0, stream>>>(Abf, wqT, Qraw, M, Dd, Dd);
    gemm_bt<true><<<dim3(1024 / 128, M / 128), 256, 0, stream>>>(Abf, kvT, KVraw, M, 1024, Dd);

    const float scale = 0.08838834764831845f;  // 1/sqrt(128), folded into Q
    int totQ = Bb * Ss * Hh * 64;
    rope_bf<<<totQ / 256, 256, 0, stream>>>(Qraw, cosT, sinT, 4, Dd, scale, totQ);
    int totK = Bb * Ss * KVHh * 64;
    rope_bf<<<totK / 256, 256, 0, stream>>>(KVraw, cosT, sinT, 2, 1024, 1.0f, totK);

    vt_cast_bf<<<dim3(Ss / 32, HDd / 32, Bb * KVHh), 256, 0, stream>>>(KVraw, VT);

    flash_attn<<<dim3(64, Hh, Bb), 64, 0, stream>>>(Qraw, KVraw, VT, alibi, amask, Ctx);

    gemm_bt<false><<<dim3(Dd / 128, M / 128), 256, 0, stream>>>(Ctx, woT, out, M, Dd, Dd);
}